// Round 5
// baseline (3431.148 us; speedup 1.0000x reference)
//
#include <hip/hip_runtime.h>
#include <math.h>

#define Hh  8
#define Dd  512
#define SUB 256          // D/2
#define Nk  1024         // num_subkeys
#define TK  32           // top_k
#define Rr  8            // rows (b,c) per block
#define NT  256
#define W_ELEMS (65536 * 32)

// Phase-1 arithmetic: single accumulator per (row,key), strictly sequential
// FUSED-FMA chain over the contraction dim in natural order (d = 0..255) —
// bit-identical to all previous rounds.
//
// R5 structural changes (no arithmetic change):
//  - NO dynamic register indexing anywhere (R3/R4 scratch traffic came from
//    the allocator demoting dynamically-indexed va[]/vb[] to scratch):
//    top-k elimination is a static unrolled cndmask loop.
//  - Selection layout: lane l owns keys [16l,16l+16) -> global pos is
//    monotone in (lane, i), so tie-break (lowest flat index, XLA semantics)
//    = lowest lane via __ballot + ctz. Wave max is a VALUE-only DPP
//    max-reduce (6 v_max_f32 + readlane) -> ZERO DS ops in the hot loop.
//  - sc[] stored XOR-swizzled (element k at column k ^ (((k>>4)&7)<<2)) so
//    the lane-owns-16 ds_read_b128 pattern is bank-conflict-free (verified:
//    writer 2 lanes/bank = free; reader 8 lanes per 4-bank group = free).
//  - q broadcast from LDS once per (js,c,row) feeding all 4 key groups.

__device__ __forceinline__ float wave_fmax_bcast(float x) {
    // classic gfx9 DPP max-reduce; result broadcast via readlane(63).
    int v;
    v = __builtin_amdgcn_update_dpp(0xff800000, __float_as_int(x), 0x111, 0xf, 0xf, false);
    x = fmaxf(x, __int_as_float(v));   // row_shr:1
    v = __builtin_amdgcn_update_dpp(0xff800000, __float_as_int(x), 0x112, 0xf, 0xf, false);
    x = fmaxf(x, __int_as_float(v));   // row_shr:2
    v = __builtin_amdgcn_update_dpp(0xff800000, __float_as_int(x), 0x114, 0xf, 0xf, false);
    x = fmaxf(x, __int_as_float(v));   // row_shr:4
    v = __builtin_amdgcn_update_dpp(0xff800000, __float_as_int(x), 0x118, 0xf, 0xf, false);
    x = fmaxf(x, __int_as_float(v));   // row_shr:8  -> lane15 of each row16 = row max
    v = __builtin_amdgcn_update_dpp(0xff800000, __float_as_int(x), 0x142, 0xa, 0xf, false);
    x = fmaxf(x, __int_as_float(v));   // row_bcast:15 -> lanes 31/63 accumulate
    v = __builtin_amdgcn_update_dpp(0xff800000, __float_as_int(x), 0x143, 0xc, 0xf, false);
    x = fmaxf(x, __int_as_float(v));   // row_bcast:31 -> lane 63 = wave max
    return __int_as_float(__builtin_amdgcn_readlane(__float_as_int(x), 63));
}

__global__ __launch_bounds__(NT, 3)
void pk_kernel(const float* __restrict__ query,
               const float* __restrict__ keyl,
               const float* __restrict__ keyr,
               float* __restrict__ out)
{
    __shared__ __attribute__((aligned(16))) float qs[Rr][Dd];   // 16 KB
    __shared__ __attribute__((aligned(16))) float sc[Rr][Nk];   // 32 KB (swizzled cols)
    __shared__ __attribute__((aligned(16))) float topv[2][Rr][TK]; // 2 KB
    __shared__ __attribute__((aligned(16))) int   topi[2][Rr][TK]; // 2 KB

    const int bid  = blockIdx.x;
    const int h    = bid >> 10;           // h-major for L2 key locality
    const int tile = bid & 1023;
    const int bc0  = tile * Rr;
    const int t    = threadIdx.x;
    const int lane = t & 63;
    const int wave = t >> 6;

    // ---- stage query tile to LDS, fully coalesced ----
    #pragma unroll
    for (int rw = 0; rw < 2; ++rw) {
        const int r = wave * 2 + rw;
        const float4* src = (const float4*)(query + ((size_t)(bc0 + r) * Hh + h) * Dd);
        float4* dst = (float4*)qs[r];
        dst[lane]      = src[lane];
        dst[lane + 64] = src[lane + 64];
    }
    __syncthreads();

    const int X = ((t >> 4) & 7) << 2;    // store-swizzle for this thread

    for (int side = 0; side < 2; ++side) {
        const float* kbase = (side == 0 ? keyl : keyr) + (size_t)h * Nk * SUB;

        const float4* kr0 = (const float4*)(kbase + (size_t)(0 * 256 + t) * SUB);
        const float4* kr1 = (const float4*)(kbase + (size_t)(1 * 256 + t) * SUB);
        const float4* kr2 = (const float4*)(kbase + (size_t)(2 * 256 + t) * SUB);
        const float4* kr3 = (const float4*)(kbase + (size_t)(3 * 256 + t) * SUB);

        float acc[Rr][4];
        #pragma unroll
        for (int r = 0; r < Rr; ++r)
            #pragma unroll
            for (int g = 0; g < 4; ++g) acc[r][g] = 0.0f;

        // ---- phase 1: q broadcast from LDS once per (js,c,row), 4 keys/thread ----
        #pragma unroll 1
        for (int js = 0; js < 16; ++js) {
            #pragma unroll
            for (int c = 0; c < 4; ++c) {
                const int idx = 4 * js + c;
                float4 k0 = kr0[idx], k1 = kr1[idx], k2 = kr2[idx], k3 = kr3[idx];
                #pragma unroll
                for (int r = 0; r < Rr; ++r) {
                    float4 qv = ((const float4*)&qs[r][side * SUB])[idx];
                    acc[r][0] = fmaf(qv.x, k0.x, acc[r][0]);
                    acc[r][1] = fmaf(qv.x, k1.x, acc[r][1]);
                    acc[r][2] = fmaf(qv.x, k2.x, acc[r][2]);
                    acc[r][3] = fmaf(qv.x, k3.x, acc[r][3]);
                    acc[r][0] = fmaf(qv.y, k0.y, acc[r][0]);
                    acc[r][1] = fmaf(qv.y, k1.y, acc[r][1]);
                    acc[r][2] = fmaf(qv.y, k2.y, acc[r][2]);
                    acc[r][3] = fmaf(qv.y, k3.y, acc[r][3]);
                    acc[r][0] = fmaf(qv.z, k0.z, acc[r][0]);
                    acc[r][1] = fmaf(qv.z, k1.z, acc[r][1]);
                    acc[r][2] = fmaf(qv.z, k2.z, acc[r][2]);
                    acc[r][3] = fmaf(qv.z, k3.z, acc[r][3]);
                    acc[r][0] = fmaf(qv.w, k0.w, acc[r][0]);
                    acc[r][1] = fmaf(qv.w, k1.w, acc[r][1]);
                    acc[r][2] = fmaf(qv.w, k2.w, acc[r][2]);
                    acc[r][3] = fmaf(qv.w, k3.w, acc[r][3]);
                }
            }
        }
        // swizzled store: element k = g*256+t goes to column k ^ (((k>>4)&7)<<2)
        #pragma unroll
        for (int r = 0; r < Rr; ++r)
            #pragma unroll
            for (int g = 0; g < 4; ++g)
                sc[r][g * 256 + (t ^ X)] = acc[r][g];
        __syncthreads();

        // ---- phase 2: exact top-32 per row; lane owns keys [16l,16l+16) ----
        {
            const int ra = wave, rb = wave + 4;
            float va[16], vb[16];
            const float4* spa = (const float4*)sc[ra];
            const float4* spb = (const float4*)sc[rb];
            #pragma unroll
            for (int c = 0; c < 4; ++c) {
                const int gidx = (4 * lane + c) ^ (lane & 7);   // swizzled granule
                float4 xa = spa[gidx], xb = spb[gidx];
                va[4*c+0] = xa.x; va[4*c+1] = xa.y; va[4*c+2] = xa.z; va[4*c+3] = xa.w;
                vb[4*c+0] = xb.x; vb[4*c+1] = xb.y; vb[4*c+2] = xb.z; vb[4*c+3] = xb.w;
            }
            for (int it = 0; it < TK; ++it) {
                float la = va[0]; int ia = 0;
                float lb = vb[0]; int ib = 0;
                #pragma unroll
                for (int i = 1; i < 16; ++i) {
                    if (va[i] > la) { la = va[i]; ia = i; }   // strict > : lowest i on ties
                    if (vb[i] > lb) { lb = vb[i]; ib = i; }
                }
                float Ma = wave_fmax_bcast(la);
                float Mb = wave_fmax_bcast(lb);
                const int wa = (int)__builtin_ctzll(__ballot(la == Ma)); // lowest lane = lowest pos
                const int wb = (int)__builtin_ctzll(__ballot(lb == Mb));
                if (lane == wa) { topv[side][ra][it] = Ma; topi[side][ra][it] = (lane << 4) | ia; }
                if (lane == wb) { topv[side][rb][it] = Mb; topi[side][rb][it] = (lane << 4) | ib; }
                const bool ka = (lane == wa), kb = (lane == wb);
                #pragma unroll
                for (int i = 0; i < 16; ++i) {                 // static-index elimination
                    va[i] = (ka && i == ia) ? -INFINITY : va[i];
                    vb[i] = (kb && i == ib) ? -INFINITY : vb[i];
                }
            }
        }
        __syncthreads();
    }

    // ---- phase 3: 32x32 product sums, top-32, softmax; lane owns p in [16l,16l+16) ----
    {
        const int ra = wave, rb = wave + 4;
        float va[16], vb[16];
        // p = 16*lane + i ; a = p>>5 = lane>>1 ; b = p&31 = 16*(lane&1)+i
        const float tla = topv[0][ra][lane >> 1];
        const float tlb = topv[0][rb][lane >> 1];
        const float4* t1a = (const float4*)topv[1][ra];
        const float4* t1b = (const float4*)topv[1][rb];
        #pragma unroll
        for (int c = 0; c < 4; ++c) {
            float4 xa = t1a[4 * (lane & 1) + c];
            float4 xb = t1b[4 * (lane & 1) + c];
            va[4*c+0] = __fadd_rn(tla, xa.x); va[4*c+1] = __fadd_rn(tla, xa.y);
            va[4*c+2] = __fadd_rn(tla, xa.z); va[4*c+3] = __fadd_rn(tla, xa.w);
            vb[4*c+0] = __fadd_rn(tlb, xb.x); vb[4*c+1] = __fadd_rn(tlb, xb.y);
            vb[4*c+2] = __fadd_rn(tlb, xb.z); vb[4*c+3] = __fadd_rn(tlb, xb.w);
        }
        float m0a = 0.0f, wva = 0.0f; int wpa = 0;
        float m0b = 0.0f, wvb = 0.0f; int wpb = 0;
        for (int it = 0; it < TK; ++it) {
            float la = va[0]; int ia = 0;
            float lb = vb[0]; int ib = 0;
            #pragma unroll
            for (int i = 1; i < 16; ++i) {
                if (va[i] > la) { la = va[i]; ia = i; }
                if (vb[i] > lb) { lb = vb[i]; ib = i; }
            }
            float Ma = wave_fmax_bcast(la);
            float Mb = wave_fmax_bcast(lb);
            const int wa = (int)__builtin_ctzll(__ballot(la == Ma));
            const int wb = (int)__builtin_ctzll(__ballot(lb == Mb));
            const int pa = (wa << 4) | __builtin_amdgcn_readlane(ia, wa);  // uniform
            const int pb = (wb << 4) | __builtin_amdgcn_readlane(ib, wb);
            if (it == 0) { m0a = Ma; m0b = Mb; }          // rank 0 = max
            if (lane == it) { wva = Ma; wpa = pa; wvb = Mb; wpb = pb; }
            const bool ka = (lane == wa), kb = (lane == wb);
            #pragma unroll
            for (int i = 0; i < 16; ++i) {
                va[i] = (ka && i == ia) ? -INFINITY : va[i];
                vb[i] = (kb && i == ib) ? -INFINITY : vb[i];
            }
        }
        float ea = (lane < TK) ? expf(wva - m0a) : 0.0f;
        float eb = (lane < TK) ? expf(wvb - m0b) : 0.0f;
        float sa = ea, sb = eb;
        #pragma unroll
        for (int m = 1; m < 64; m <<= 1) {
            sa += __shfl_xor(sa, m, 64);
            sb += __shfl_xor(sb, m, 64);
        }
        if (lane < TK) {
            {
                const int bc = bc0 + ra;
                const size_t base = ((size_t)bc * Hh + h) * TK;
                const int a = wpa >> 5;
                // reference quirk: product_indices[a*32+b] = l[a]*N + r[a]
                const int fl = topi[0][ra][a] * Nk + topi[1][ra][a];
                out[base + lane] = ea / sa;
                out[(size_t)W_ELEMS + base + lane] = (float)fl;
            }
            {
                const int bc = bc0 + rb;
                const size_t base = ((size_t)bc * Hh + h) * TK;
                const int a = wpb >> 5;
                const int fl = topi[0][rb][a] * Nk + topi[1][rb][a];
                out[base + lane] = eb / sb;
                out[(size_t)W_ELEMS + base + lane] = (float)fl;
            }
        }
    }
}

extern "C" void kernel_launch(void* const* d_in, const int* in_sizes, int n_in,
                              void* d_out, int out_size, void* d_ws, size_t ws_size,
                              hipStream_t stream)
{
    const float* query = (const float*)d_in[0];
    const float* keyl  = (const float*)d_in[1];
    const float* keyr  = (const float*)d_in[2];
    float* out = (float*)d_out;
    pk_kernel<<<dim3(8192), dim3(NT), 0, stream>>>(query, keyl, keyr, out);
}